// Round 3
// baseline (5908.289 us; speedup 1.0000x reference)
//
#include <hip/hip_runtime.h>
#include <stdint.h>
#include <stddef.h>

// ---- problem constants ----
#define TT   1024
#define BB   32
#define II   1024
#define HH   1024
#define NHH  8
#define HSS  128
#define N4   4096   // NH*4*HS

// ---------------- prep: transpose Whh to [head][k][n], zero states ----------
__global__ void prep_kernel(const float* __restrict__ whh, float* __restrict__ whhT,
                            float* __restrict__ st, float* __restrict__ hst) {
  int idx = blockIdx.x * blockDim.x + threadIdx.x;
  int stride = gridDim.x * blockDim.x;
  // whh flat: [head][n][k], n in [0,512), k in [0,128)
  for (int i = idx; i < NHH * 512 * HSS; i += stride) {
    int head = i >> 16;           // /(512*128)
    int rem = i & 65535;
    int n = rem >> 7, k = rem & 127;
    whhT[(size_t)(head * HSS + k) * 512 + n] = whh[i];
  }
  for (int i = idx; i < 3 * BB * NHH * HSS; i += stride) st[i] = 0.0f;
  for (int i = idx; i < BB * NHH * HSS; i += stride) hst[i] = 0.0f;
}

// ---------------- gates GEMM, pure fp32 VALU ----------------
// C[m][n] = sum_k A[m][k]*Bt[n][k] + bias[n]
// A [M][1024] row-major (xs chunk), Bt [4096][1024] (W_ih as-is), C [M][4096].
// 128x128 tile, 256 threads, 8x8 outputs/thread, KT=16, fold partials every 128 k.
__global__ __launch_bounds__(256) void gemm_gates_f32(
    const float* __restrict__ A, const float* __restrict__ Bt,
    const float* __restrict__ bias, float* __restrict__ C, int M) {
  __shared__ float As[16][132];
  __shared__ float Bs[16][132];
  const int tid = threadIdx.x;
  const int tx = tid & 15, ty = tid >> 4;
  const long row0 = (long)blockIdx.y * 128;
  const long col0 = (long)blockIdx.x * 128;
  const int sr = tid >> 2;        // 0..63
  const int sk = (tid & 3) * 4;   // 0,4,8,12

  float acc[8][8], accL[8][8];
#pragma unroll
  for (int i = 0; i < 8; ++i)
#pragma unroll
    for (int j = 0; j < 8; ++j) { acc[i][j] = 0.0f; accL[i][j] = 0.0f; }

  float bcol[8];
#pragma unroll
  for (int j = 0; j < 8; ++j) bcol[j] = bias[col0 + tx * 8 + j];

  for (int kt = 0; kt < 64; ++kt) {
    const int k0 = kt * 16;
    float4 a0 = *(const float4*)&A[(row0 + sr) * 1024 + k0 + sk];
    float4 a1 = *(const float4*)&A[(row0 + sr + 64) * 1024 + k0 + sk];
    float4 b0 = *(const float4*)&Bt[(col0 + sr) * 1024 + k0 + sk];
    float4 b1 = *(const float4*)&Bt[(col0 + sr + 64) * 1024 + k0 + sk];

    As[sk + 0][sr] = a0.x; As[sk + 1][sr] = a0.y; As[sk + 2][sr] = a0.z; As[sk + 3][sr] = a0.w;
    As[sk + 0][sr + 64] = a1.x; As[sk + 1][sr + 64] = a1.y; As[sk + 2][sr + 64] = a1.z; As[sk + 3][sr + 64] = a1.w;
    Bs[sk + 0][sr] = b0.x; Bs[sk + 1][sr] = b0.y; Bs[sk + 2][sr] = b0.z; Bs[sk + 3][sr] = b0.w;
    Bs[sk + 0][sr + 64] = b1.x; Bs[sk + 1][sr + 64] = b1.y; Bs[sk + 2][sr + 64] = b1.z; Bs[sk + 3][sr + 64] = b1.w;
    __syncthreads();

#pragma unroll
    for (int kk = 0; kk < 16; ++kk) {
      float av[8], bv[8];
      *(float4*)&av[0] = *(const float4*)&As[kk][ty * 8];
      *(float4*)&av[4] = *(const float4*)&As[kk][ty * 8 + 4];
      *(float4*)&bv[0] = *(const float4*)&Bs[kk][tx * 8];
      *(float4*)&bv[4] = *(const float4*)&Bs[kk][tx * 8 + 4];
#pragma unroll
      for (int i = 0; i < 8; ++i)
#pragma unroll
        for (int j = 0; j < 8; ++j) accL[i][j] += av[i] * bv[j];
    }
    __syncthreads();

    if ((kt & 7) == 7) {  // fold every 128 k: bounds accumulation-rounding walk
#pragma unroll
      for (int i = 0; i < 8; ++i)
#pragma unroll
        for (int j = 0; j < 8; ++j) { acc[i][j] += accL[i][j]; accL[i][j] = 0.0f; }
    }
  }

#pragma unroll
  for (int i = 0; i < 8; ++i) {
    long row = row0 + ty * 8 + i;
    float4 o0, o1;
    o0.x = acc[i][0] + bcol[0]; o0.y = acc[i][1] + bcol[1];
    o0.z = acc[i][2] + bcol[2]; o0.w = acc[i][3] + bcol[3];
    o1.x = acc[i][4] + bcol[4]; o1.y = acc[i][5] + bcol[5];
    o1.z = acc[i][6] + bcol[6]; o1.w = acc[i][7] + bcol[7];
    *(float4*)&C[row * N4 + col0 + tx * 8] = o0;
    *(float4*)&C[row * N4 + col0 + tx * 8 + 4] = o1;
  }
}

// ---------------- sequential scan, pure fp32 ----------------
// 256 blocks = head*32 + b. 512 threads; thread n owns output col n (gate g=n>>7,
// d=n&127), W_hh row pinned in 128 VGPRs. h broadcast via LDS. Threads 0..127
// hold c/n/m state for d and do the elementwise update.
__global__ __launch_bounds__(512) void scan_f32(
    const float* __restrict__ gates, const float* __restrict__ whhT,
    float* __restrict__ out,
    float* __restrict__ stc, float* __restrict__ stn, float* __restrict__ stm,
    float* __restrict__ hst, int t0, int chp) {
  __shared__ float hbuf[128];
  __shared__ float pre[512];
  const int tid = threadIdx.x;
  const int head = blockIdx.x >> 5, b = blockIdx.x & 31;

  float W[128];
#pragma unroll
  for (int k = 0; k < 128; ++k) W[k] = whhT[(size_t)(head * HSS + k) * 512 + tid];

  float c = 0.f, nn = 0.f, m = 0.f;
  if (tid < 128) {
    int si = (b * NHH + head) * HSS + tid;
    c = stc[si]; nn = stn[si]; m = stm[si];
    hbuf[tid] = hst[si];
  }
  __syncthreads();

  const size_t gbase = (size_t)b * N4 + head * 512 + tid;
  float gcur = gates[gbase];

  for (int t = 0; t < chp; ++t) {
    float gnext = 0.0f;
    if (t + 1 < chp) gnext = gates[gbase + (size_t)(t + 1) * 32 * N4];

    float a0 = 0.f, a1 = 0.f;
#pragma unroll
    for (int k4 = 0; k4 < 16; ++k4) {
      float4 h0 = *(const float4*)&hbuf[k4 * 4];
      float4 h1 = *(const float4*)&hbuf[64 + k4 * 4];
      a0 += W[k4 * 4 + 0] * h0.x; a0 += W[k4 * 4 + 1] * h0.y;
      a0 += W[k4 * 4 + 2] * h0.z; a0 += W[k4 * 4 + 3] * h0.w;
      a1 += W[64 + k4 * 4 + 0] * h1.x; a1 += W[64 + k4 * 4 + 1] * h1.y;
      a1 += W[64 + k4 * 4 + 2] * h1.z; a1 += W[64 + k4 * 4 + 3] * h1.w;
    }
    pre[tid] = gcur + (a0 + a1);
    __syncthreads();

    if (tid < 128) {
      float iv = pre[tid], fv = pre[128 + tid], zv = pre[256 + tid], ov = pre[384 + tid];
      float a = fv + m;
      float mn = fmaxf(a, iv);
      float fe = expf(a - mn);
      float ie = expf(iv - mn);
      float zt = tanhf(zv);
      float og = 1.0f / (1.0f + expf(-ov));
      c = fe * c + ie * zt;
      nn = fe * nn + ie;
      m = mn;
      float h = og * (c / nn);
      out[(size_t)(t0 + t) * (BB * HH) + (size_t)b * HH + head * HSS + tid] = h;
      hbuf[tid] = h;
    }
    __syncthreads();
    gcur = gnext;
  }

  if (tid < 128) {
    int si = (b * NHH + head) * HSS + tid;
    stc[si] = c; stn[si] = nn; stm[si] = m;
    hst[si] = hbuf[tid];
  }
}

// ---------------- launcher ----------------
// ws: whhT 2MB | stc/stn/stm 128KB ea | hst 128KB | gates ch*512KB
extern "C" void kernel_launch(void* const* d_in, const int* in_sizes, int n_in,
                              void* d_out, int out_size, void* d_ws, size_t ws_size,
                              hipStream_t stream) {
  const float* xs   = (const float*)d_in[0];
  const float* wih  = (const float*)d_in[1];
  const float* whh  = (const float*)d_in[2];
  const float* bias = (const float*)d_in[3];
  float* out = (float*)d_out;
  char* ws = (char*)d_ws;

  float* whhT = (float*)(ws + 0);
  float* stc  = (float*)(ws + 2097152);
  float* stn  = (float*)(ws + 2228224);
  float* stm  = (float*)(ws + 2359296);
  float* hst  = (float*)(ws + 2490368);
  const size_t base = 2621440;

  int ch = 256;
  while (ch > 8) {
    if (base + (size_t)ch * 524288 <= ws_size) break;
    ch >>= 1;
  }
  float* gts = (float*)(ws + base);
  const int nch = TT / ch;

  prep_kernel<<<256, 256, 0, stream>>>(whh, whhT, stc, hst);

  for (int cix = 0; cix < nch; ++cix) {
    dim3 g(32, (unsigned)(ch / 4));
    gemm_gates_f32<<<g, 256, 0, stream>>>(xs + (size_t)cix * ch * BB * II, wih,
                                          bias, gts, 32 * ch);
    scan_f32<<<256, 512, 0, stream>>>(gts, whhT, out, stc, stn, stm, hst,
                                      cix * ch, ch);
  }
}